// Round 8
// baseline (29.337 us; speedup 1.0000x reference)
//
#include <hip/hip_runtime.h>

// Chamfer loss: pred (8,4096,3) f32, target (8,4096,3) f32 -> scalar f32.
// dist = |q|^2 + (|t|^2 - 2 q.t). Inner loop processes 2 targets/query with
// 3 v_pk_fma_f32 + 1 v_min3_f32 (2 instr/pair): LDS tile is pair-packed as
// pairA=(x0,x1,y0,y1), pairB=(z0,z1,w0,w1); d2 = pk_fma chain seeded from
// (w0,w1); |q|^2 added after the cross-slice min.
//
// Round-8: identical structure to round 7 (512 blocks x 512 thr, 2 LDS
// phases, in-block cross-slice reduce, 2 graph nodes) with the inner loop
// switched from 3.5 scalar instr/pair to 2 packed instr/pair.

typedef float v2f __attribute__((ext_vector_type(2)));

#define BATCH 8
#define NPTS  4096
#define TPB   512
#define QPT   8                       // queries per thread
#define NQG   16                      // query groups per block
#define QB    (NQG * QPT)             // 128 queries per block
#define NSL   32                      // target slices per block
#define NBLK  (2 * BATCH * (NPTS / QB))  // 512 blocks
#define PHPTS 2048                    // targets staged per phase
#define NPAIR (PHPTS / 2)             // 1024 pairs per phase
#define SPAIR (NPAIR / NSL)           // 32 pairs per slice per phase

// per 2 targets: 2 uniform ds_read_b128 + per query 3 pk_fma + 1 min3.
#define INNER_LOOP(PA, PB)                                                    \
    _Pragma("unroll 4")                                                       \
    for (int j = 0; j < SPAIR; ++j) {                                         \
        float4 A = (PA)[j];                                                   \
        float4 B = (PB)[j];                                                   \
        v2f xy = {A.x, A.y}, yz = {A.z, A.w};                                 \
        v2f zz = {B.x, B.y}, ww = {B.z, B.w};                                 \
        _Pragma("unroll")                                                     \
        for (int k = 0; k < QPT; ++k) {                                       \
            v2f d = __builtin_elementwise_fma(az2[k], zz, ww);                \
            d = __builtin_elementwise_fma(ay2[k], yz, d);                     \
            d = __builtin_elementwise_fma(ax2[k], xy, d);                     \
            mn[k] = fminf(fminf(d.x, d.y), mn[k]);    /* v_min3_f32 */        \
        }                                                                     \
    }

__global__ __launch_bounds__(TPB, 4)   // 4 waves/EU -> 2 blocks/CU, VGPR<=128
void chamfer_main(const float* __restrict__ pred,
                  const float* __restrict__ tgt,
                  float* __restrict__ blkpart /* [NBLK] */)
{
    int bid = blockIdx.x;
    int dir = bid >> 8;               // 0..1
    int b   = (bid >> 5) & 7;         // batch
    int qt  = bid & 31;               // query tile of 128

    const float* qsrc = dir ? tgt  : pred;
    const float* csrc = dir ? pred : tgt;

    __shared__ float4 pA[NPAIR];      // (x0,x1,y0,y1) 16 KB
    __shared__ float4 pB[NPAIR];      // (z0,z1,w0,w1) 16 KB
    __shared__ float  acc[TPB / 64];

    int tid = threadIdx.x;
    int qg  = tid & (NQG - 1);        // fast index -> 4 distinct slices/wave
    int sl  = tid >> 4;

    // ---- this thread's 8 consecutive queries: 6 coalesced dwordx4 ----
    const float4* q4 = reinterpret_cast<const float4*>(
        qsrc + ((size_t)b * NPTS + (size_t)qt * QB) * 3);
    float4 v0 = q4[qg * 6 + 0];
    float4 v1 = q4[qg * 6 + 1];
    float4 v2 = q4[qg * 6 + 2];
    float4 v3 = q4[qg * 6 + 3];
    float4 v4 = q4[qg * 6 + 4];
    float4 v5 = q4[qg * 6 + 5];

    v2f ax2[QPT], ay2[QPT], az2[QPT];
    float mn[QPT];
    {
        float qx[QPT], qy[QPT], qz[QPT];
        qx[0]=v0.x; qy[0]=v0.y; qz[0]=v0.z;
        qx[1]=v0.w; qy[1]=v1.x; qz[1]=v1.y;
        qx[2]=v1.z; qy[2]=v1.w; qz[2]=v2.x;
        qx[3]=v2.y; qy[3]=v2.z; qz[3]=v2.w;
        qx[4]=v3.x; qy[4]=v3.y; qz[4]=v3.z;
        qx[5]=v3.w; qy[5]=v4.x; qz[5]=v4.y;
        qx[6]=v4.z; qy[6]=v4.w; qz[6]=v5.x;
        qx[7]=v5.y; qy[7]=v5.z; qz[7]=v5.w;
#pragma unroll
        for (int i = 0; i < QPT; ++i) {
            float ax = -2.0f * qx[i], ay = -2.0f * qy[i], az = -2.0f * qz[i];
            ax2[i] = (v2f){ax, ax};
            ay2[i] = (v2f){ay, ay};
            az2[i] = (v2f){az, az};
            mn[i]  = 3.0e38f;
        }
    }

    const float4* t4 = reinterpret_cast<const float4*>(csrc + (size_t)b * NPTS * 3);

    // ---- phase 0 staging: 4 points (2 pairs) per thread, 3 dwordx4 in ----
    {
        float4 r0 = t4[tid * 3 + 0];
        float4 r1 = t4[tid * 3 + 1];
        float4 r2 = t4[tid * 3 + 2];
        float w0 = r0.x*r0.x + r0.y*r0.y + r0.z*r0.z;
        float w1 = r0.w*r0.w + r1.x*r1.x + r1.y*r1.y;
        float w2 = r1.z*r1.z + r1.w*r1.w + r2.x*r2.x;
        float w3 = r2.y*r2.y + r2.z*r2.z + r2.w*r2.w;
        pA[tid*2+0] = make_float4(r0.x, r0.w, r0.y, r1.x);
        pB[tid*2+0] = make_float4(r0.z, r1.y, w0, w1);
        pA[tid*2+1] = make_float4(r1.z, r2.y, r1.w, r2.z);
        pB[tid*2+1] = make_float4(r2.x, r2.w, w2, w3);
    }
    __syncthreads();

    // phase-1 staging loads issued now; latency hides under phase-0 compute
    float4 s0 = t4[1536 + tid * 3 + 0];
    float4 s1 = t4[1536 + tid * 3 + 1];
    float4 s2 = t4[1536 + tid * 3 + 2];

    {
        const float4* a = pA + sl * SPAIR;
        const float4* c = pB + sl * SPAIR;
        INNER_LOOP(a, c)
    }
    __syncthreads();                   // all reads of phase-0 tiles done

    {
        float w0 = s0.x*s0.x + s0.y*s0.y + s0.z*s0.z;
        float w1 = s0.w*s0.w + s1.x*s1.x + s1.y*s1.y;
        float w2 = s1.z*s1.z + s1.w*s1.w + s2.x*s2.x;
        float w3 = s2.y*s2.y + s2.z*s2.z + s2.w*s2.w;
        pA[tid*2+0] = make_float4(s0.x, s0.w, s0.y, s1.x);
        pB[tid*2+0] = make_float4(s0.z, s1.y, w0, w1);
        pA[tid*2+1] = make_float4(s1.z, s2.y, s1.w, s2.z);
        pB[tid*2+1] = make_float4(s2.x, s2.w, w2, w3);
    }
    __syncthreads();

    {
        const float4* a = pA + sl * SPAIR;
        const float4* c = pB + sl * SPAIR;
        INNER_LOOP(a, c)
    }
    __syncthreads();                   // compute done; pA reusable as scratch

    // ---- in-block cross-slice reduce ----
    float* scratch = (float*)pA;       // [NSL][QB] floats = 16 KB
#pragma unroll
    for (int r = 0; r < QPT; ++r)
        scratch[sl * QB + qg * QPT + r] = mn[r];
    __syncthreads();

    float val = 0.0f;
    if (tid < QB) {                    // one query per thread
        float m = scratch[tid];
#pragma unroll 8
        for (int s = 1; s < NSL; ++s)
            m = fminf(m, scratch[s * QB + tid]);   // lane-contiguous
        const float* qp = qsrc + ((size_t)b * NPTS + (size_t)qt * QB + tid) * 3;
        float x = qp[0], y = qp[1], z = qp[2];     // L1-hot
        val = x*x + y*y + z*z + m;
    }
#pragma unroll
    for (int o = 32; o; o >>= 1) val += __shfl_down(val, o);
    int lane = tid & 63, wid = tid >> 6;
    if (lane == 0) acc[wid] = val;
    __syncthreads();
    if (tid == 0) {
        float s = 0.0f;
#pragma unroll
        for (int i = 0; i < TPB / 64; ++i) s += acc[i];
        blkpart[bid] = s;
    }
}

// node 2: sum 512 block partials, write scalar (plain store, deterministic).
__global__ __launch_bounds__(TPB)
void chamfer_final(const float* __restrict__ blkpart,
                   float* __restrict__ out)
{
    float s = blkpart[threadIdx.x];
#pragma unroll
    for (int o = 32; o; o >>= 1) s += __shfl_down(s, o);
    __shared__ float acc[TPB / 64];
    int lane = threadIdx.x & 63, wid = threadIdx.x >> 6;
    if (lane == 0) acc[wid] = s;
    __syncthreads();
    if (threadIdx.x == 0) {
        float t = 0.0f;
#pragma unroll
        for (int i = 0; i < TPB / 64; ++i) t += acc[i];
        out[0] = t * (1.0f / (BATCH * NPTS));
    }
}

// ---- fallback (no usable ws): block owns 256 queries over full M ----
#define FTPB  256
#define CHUNK 512
#define NCH   (NPTS / CHUNK)

__global__ __launch_bounds__(FTPB)
void chamfer_fallback(const float* __restrict__ pred,
                      const float* __restrict__ tgt,
                      float* __restrict__ out)
{
    int bid = blockIdx.x;
    const int per_dir = BATCH * (NPTS / FTPB);
    int dir = bid / per_dir;
    int r   = bid - dir * per_dir;
    int b   = r / (NPTS / FTPB);
    int qt  = r % (NPTS / FTPB);

    const float* qsrc = dir ? tgt  : pred;
    const float* csrc = dir ? pred : tgt;

    __shared__ float4 sc[CHUNK];
    int q = qt * FTPB + threadIdx.x;
    const float* qp = qsrc + (size_t)(b * NPTS + q) * 3;
    float x = qp[0], y = qp[1], z = qp[2];
    float ax = -2.0f * x, ay = -2.0f * y, az = -2.0f * z;
    float w = x * x + y * y + z * z;
    float mn = 3.0e38f;

    for (int ch = 0; ch < NCH; ++ch) {
        __syncthreads();
        const float* cbase = csrc + (size_t)(b * NPTS + ch * CHUNK) * 3;
        for (int p = threadIdx.x; p < CHUNK; p += FTPB) {
            float tx = cbase[3 * p + 0];
            float ty = cbase[3 * p + 1];
            float tz = cbase[3 * p + 2];
            sc[p] = make_float4(tx, ty, tz, tx * tx + ty * ty + tz * tz);
        }
        __syncthreads();
#pragma unroll 4
        for (int j = 0; j < CHUNK; ++j) {
            float4 t = sc[j];
            float d = fmaf(az, t.z, fmaf(ay, t.y, fmaf(ax, t.x, t.w)));
            mn = fminf(mn, d);
        }
    }
    mn += w;
#pragma unroll
    for (int o = 32; o; o >>= 1) mn += __shfl_down(mn, o);
    __shared__ float acc[FTPB / 64];
    int lane = threadIdx.x & 63, wid = threadIdx.x >> 6;
    if (lane == 0) acc[wid] = mn;
    __syncthreads();
    if (threadIdx.x == 0) {
        float s = 0.0f;
#pragma unroll
        for (int i = 0; i < FTPB / 64; ++i) s += acc[i];
        atomicAdd(out, s * (1.0f / (BATCH * NPTS)));
    }
}

extern "C" void kernel_launch(void* const* d_in, const int* in_sizes, int n_in,
                              void* d_out, int out_size, void* d_ws, size_t ws_size,
                              hipStream_t stream)
{
    const float* pred = (const float*)d_in[0];
    const float* tgt  = (const float*)d_in[1];
    float* out = (float*)d_out;

    if (ws_size >= NBLK * sizeof(float)) {
        float* blkpart = (float*)d_ws;
        chamfer_main<<<NBLK, TPB, 0, stream>>>(pred, tgt, blkpart);
        chamfer_final<<<1, TPB, 0, stream>>>(blkpart, out);
    } else {
        hipMemsetAsync(d_out, 0, sizeof(float), stream);
        chamfer_fallback<<<2 * BATCH * (NPTS / FTPB), FTPB, 0, stream>>>(pred, tgt, out);
    }
}